// Round 1
// baseline (986.615 us; speedup 1.0000x reference)
//
#include <hip/hip_runtime.h>
#include <hip/hip_bf16.h>
#include <stdint.h>

// HBitLinear: out = ((quant4(x@H))@H) @ (ternary(W))^T + bias
// D=4096, rows = B*S = 8192. H = Sylvester Hadamard / 64 (symmetric).

#define D_DIM 4096

typedef __attribute__((ext_vector_type(8))) short bf16x8;   // 8 bf16 = 4 VGPRs
typedef __attribute__((ext_vector_type(4))) float f32x4;

// ---- order-preserving float<->uint keys for atomic min/max ----
__device__ __forceinline__ unsigned f2ord(float f) {
  unsigned u = __float_as_uint(f);
  return (u & 0x80000000u) ? ~u : (u | 0x80000000u);
}
__device__ __forceinline__ float ord2f(unsigned k) {
  return (k & 0x80000000u) ? __uint_as_float(k & 0x7fffffffu) : __uint_as_float(~k);
}
// float -> bf16 bits, round-nearest-even (no NaN inputs here)
__device__ __forceinline__ unsigned f2bf(float f) {
  unsigned u = __float_as_uint(f);
  return ((u + 0x7fffu + ((u >> 16) & 1u)) >> 16) & 0xffffu;
}

// ws layout: [0..63] uint scalars: keys[0]=max|W|, keys[1]=min t, keys[2]=max t
//            +256B : xq  (rows*4096 bf16)  = 64 MiB
//            +256B+64MiB : wq (4096^2 bf16, ternary +-1/0, scale folded out) = 32 MiB

__global__ void k_init(unsigned* keys) {
  keys[0] = 0u;            // max|W| key (values >= 0 -> key >= 0x80000000)
  keys[1] = 0xFFFFFFFFu;   // min t key
  keys[2] = 0u;            // max t key
}

// ---- max |W| reduce ----
__global__ __launch_bounds__(256) void k_wabs(const float* __restrict__ W, unsigned* keys) {
  float m = 0.0f;
  const int n4 = (D_DIM * D_DIM) / 4;
  for (int i = blockIdx.x * 256 + threadIdx.x; i < n4; i += gridDim.x * 256) {
    float4 v = ((const float4*)W)[i];
    m = fmaxf(m, fmaxf(fmaxf(fabsf(v.x), fabsf(v.y)), fmaxf(fabsf(v.z), fabsf(v.w))));
  }
  #pragma unroll
  for (int off = 32; off; off >>= 1) m = fmaxf(m, __shfl_down(m, off));
  __shared__ float sm[4];
  if ((threadIdx.x & 63) == 0) sm[threadIdx.x >> 6] = m;
  __syncthreads();
  if (threadIdx.x == 0) {
    m = fmaxf(fmaxf(sm[0], sm[1]), fmaxf(sm[2], sm[3]));
    atomicMax(keys + 0, f2ord(m));
  }
}

// ---- ternary weight quant: wq = 0 if |W/s|<0.5 else sign, stored as bf16 ±1 ----
__global__ __launch_bounds__(256) void k_quant_w(const float* __restrict__ W,
                                                 const unsigned* __restrict__ keys,
                                                 unsigned short* __restrict__ wq) {
  const float scale = ord2f(keys[0]);   // >0 for this input
  const int i = blockIdx.x * 256 + threadIdx.x;   // over float4
  float4 v = ((const float4*)W)[i];
  ushort4 o;
  {
    float wn = v.x / scale;
    o.x = (fabsf(wn) < 0.5f) ? 0 : ((wn < 0.0f) ? 0xBF80u : 0x3F80u);
    wn = v.y / scale;
    o.y = (fabsf(wn) < 0.5f) ? 0 : ((wn < 0.0f) ? 0xBF80u : 0x3F80u);
    wn = v.z / scale;
    o.z = (fabsf(wn) < 0.5f) ? 0 : ((wn < 0.0f) ? 0xBF80u : 0x3F80u);
    wn = v.w / scale;
    o.w = (fabsf(wn) < 0.5f) ? 0 : ((wn < 0.0f) ? 0xBF80u : 0x3F80u);
  }
  ((ushort4*)wq)[i] = o;
}

// ---- in-LDS FWHT, 12 unnormalized stages (caller applies 1/64) ----
__device__ __forceinline__ void fwht_lds(float* row, int tid) {
  #pragma unroll
  for (int s = 0; s < 12; ++s) {
    const int stride = 1 << s;
    #pragma unroll
    for (int bb = 0; bb < 8; ++bb) {
      const int b = tid + bb * 256;
      const int i = ((b >> s) << (s + 1)) | (b & (stride - 1));
      const int j = i | stride;
      const float a = row[i], c = row[j];
      row[i] = a + c;
      row[j] = a - c;
    }
    __syncthreads();
  }
}

// ---- pass 1: t = x@H per row, global min/max via atomics (t not stored) ----
__global__ __launch_bounds__(256) void k_fwht_minmax(const float* __restrict__ x,
                                                     unsigned* keys) {
  __shared__ float row[D_DIM];
  const int tid = threadIdx.x;
  const float* src = x + (size_t)blockIdx.x * D_DIM;
  #pragma unroll
  for (int i = 0; i < 4; ++i)
    ((float4*)row)[tid + i * 256] = ((const float4*)src)[tid + i * 256];
  __syncthreads();
  fwht_lds(row, tid);
  float mn = 1e30f, mx = -1e30f;
  #pragma unroll
  for (int i = 0; i < 16; ++i) {
    const float v = row[tid + i * 256] * (1.0f / 64.0f);
    mn = fminf(mn, v);
    mx = fmaxf(mx, v);
  }
  #pragma unroll
  for (int off = 32; off; off >>= 1) {
    mn = fminf(mn, __shfl_down(mn, off));
    mx = fmaxf(mx, __shfl_down(mx, off));
  }
  __shared__ float smn[4], smx[4];
  if ((tid & 63) == 0) { smn[tid >> 6] = mn; smx[tid >> 6] = mx; }
  __syncthreads();
  if (tid == 0) {
    mn = fminf(fminf(smn[0], smn[1]), fminf(smn[2], smn[3]));
    mx = fmaxf(fmaxf(smx[0], smx[1]), fmaxf(smx[2], smx[3]));
    atomicMin(keys + 1, f2ord(mn));
    atomicMax(keys + 2, f2ord(mx));
  }
}

// ---- pass 2: recompute t, 4-bit affine quant/dequant, second FWHT, pack bf16 ----
__global__ __launch_bounds__(256) void k_quant_fwht(const float* __restrict__ x,
                                                    const unsigned* __restrict__ keys,
                                                    unsigned short* __restrict__ xq) {
  __shared__ float row[D_DIM];
  const int tid = threadIdx.x;
  const float* src = x + (size_t)blockIdx.x * D_DIM;
  #pragma unroll
  for (int i = 0; i < 4; ++i)
    ((float4*)row)[tid + i * 256] = ((const float4*)src)[tid + i * 256];
  __syncthreads();
  fwht_lds(row, tid);

  const float tmin = ord2f(keys[1]);
  const float tmax = ord2f(keys[2]);
  const float scale = (tmax - tmin) / 15.0f;             // (qmax-qmin)=15
  const float zp = -8.0f - rintf(tmin / scale);          // jnp.round = rintf (half-even)
  #pragma unroll
  for (int i = 0; i < 16; ++i) {
    const int idx = tid + i * 256;
    const float t = row[idx] * (1.0f / 64.0f);
    float q = rintf(t / scale + zp);
    q = fminf(fmaxf(q, -8.0f), 7.0f);
    row[idx] = scale * (q - zp);
  }
  __syncthreads();
  fwht_lds(row, tid);

  unsigned short* dst = xq + (size_t)blockIdx.x * D_DIM;
  #pragma unroll
  for (int c = 0; c < 2; ++c) {
    const int id = c * 256 + tid;                 // 8-element chunk id
    float4 v0 = ((const float4*)row)[id * 2];
    float4 v1 = ((const float4*)row)[id * 2 + 1];
    uint4 pk;
    pk.x = f2bf(v0.x * (1.0f / 64.0f)) | (f2bf(v0.y * (1.0f / 64.0f)) << 16);
    pk.y = f2bf(v0.z * (1.0f / 64.0f)) | (f2bf(v0.w * (1.0f / 64.0f)) << 16);
    pk.z = f2bf(v1.x * (1.0f / 64.0f)) | (f2bf(v1.y * (1.0f / 64.0f)) << 16);
    pk.w = f2bf(v1.z * (1.0f / 64.0f)) | (f2bf(v1.w * (1.0f / 64.0f)) << 16);
    ((uint4*)dst)[id] = pk;
  }
}

// ---- GEMM: out[m][n] = wscale * sum_k Xq[m][k]*Wsgn[n][k] + bias[n] ----
// m97 structure: 128x128 tile, BK=32, 4 waves (2x2), 4x4 frags of 16x16x32 bf16,
// global_load_lds width 16, linear LDS, 2 barriers per K-step.
typedef const __attribute__((address_space(1))) unsigned int gu32;
typedef __attribute__((address_space(3))) unsigned int lu32;
#define GLL(g, l) __builtin_amdgcn_global_load_lds((gu32*)(g), (lu32*)(l), 16, 0, 0)

__global__ __launch_bounds__(256) void k_gemm(const unsigned short* __restrict__ Xq,
                                              const unsigned short* __restrict__ Wq,
                                              const unsigned* __restrict__ keys,
                                              const float* __restrict__ bias,
                                              float* __restrict__ out) {
  __shared__ unsigned short lA[128 * 32];
  __shared__ unsigned short lB[128 * 32];
  const int tid = threadIdx.x;
  const int wave = tid >> 6, lane = tid & 63;
  const int wr = wave >> 1, wc = wave & 1;
  const size_t rowA0 = (size_t)blockIdx.x * 128;
  const size_t rowB0 = (size_t)blockIdx.y * 128;

  // staging: element e = issue*2048 + wave*512 + lane*8 of the 128x32 tile
  const int e = wave * 512 + lane * 8;
  const int er = e >> 5, ec = e & 31;
  const unsigned short* gA0 = Xq + (rowA0 + er) * D_DIM + ec;
  const unsigned short* gA1 = Xq + (rowA0 + 64 + er) * D_DIM + ec;
  const unsigned short* gB0 = Wq + (rowB0 + er) * D_DIM + ec;
  const unsigned short* gB1 = Wq + (rowB0 + 64 + er) * D_DIM + ec;
  unsigned short* lA0 = &lA[wave * 512];
  unsigned short* lA1 = &lA[2048 + wave * 512];
  unsigned short* lB0 = &lB[wave * 512];
  unsigned short* lB1 = &lB[2048 + wave * 512];

  f32x4 acc[4][4] = {};

  for (int kt = 0; kt < D_DIM / 32; ++kt) {
    const int ko = kt * 32;
    GLL(gA0 + ko, lA0);
    GLL(gA1 + ko, lA1);
    GLL(gB0 + ko, lB0);
    GLL(gB1 + ko, lB1);
    __syncthreads();   // vmcnt(0) drain + barrier: LDS tile ready
    bf16x8 af[4], bfr[4];
    #pragma unroll
    for (int i = 0; i < 4; ++i)
      af[i] = *(const bf16x8*)&lA[(wr * 64 + i * 16 + (lane & 15)) * 32 + (lane >> 4) * 8];
    #pragma unroll
    for (int i = 0; i < 4; ++i)
      bfr[i] = *(const bf16x8*)&lB[(wc * 64 + i * 16 + (lane & 15)) * 32 + (lane >> 4) * 8];
    #pragma unroll
    for (int mi = 0; mi < 4; ++mi)
      #pragma unroll
      for (int ni = 0; ni < 4; ++ni)
        acc[mi][ni] = __builtin_amdgcn_mfma_f32_16x16x32_bf16(af[mi], bfr[ni], acc[mi][ni], 0, 0, 0);
    __syncthreads();   // all waves done reading before next stage overwrites
  }

  const float wscale = ord2f(keys[0]);
  #pragma unroll
  for (int mi = 0; mi < 4; ++mi)
    #pragma unroll
    for (int ni = 0; ni < 4; ++ni)
      #pragma unroll
      for (int r = 0; r < 4; ++r) {
        const size_t row = rowA0 + wr * 64 + mi * 16 + (lane >> 4) * 4 + r;
        const size_t col = rowB0 + wc * 64 + ni * 16 + (lane & 15);
        out[row * D_DIM + col] = acc[mi][ni][r] * wscale + bias[col];
      }
}

extern "C" void kernel_launch(void* const* d_in, const int* in_sizes, int n_in,
                              void* d_out, int out_size, void* d_ws, size_t ws_size,
                              hipStream_t stream) {
  const float* x    = (const float*)d_in[0];
  const float* W    = (const float*)d_in[1];
  const float* bias = (const float*)d_in[2];
  float* out = (float*)d_out;

  const int rows = in_sizes[0] / D_DIM;   // 8192

  unsigned* keys = (unsigned*)d_ws;
  unsigned short* xq = (unsigned short*)((char*)d_ws + 256);
  unsigned short* wq = (unsigned short*)((char*)d_ws + 256 + (size_t)rows * D_DIM * 2);

  k_init<<<1, 1, 0, stream>>>(keys);
  k_wabs<<<1024, 256, 0, stream>>>(W, keys);
  k_fwht_minmax<<<rows, 256, 0, stream>>>(x, keys);
  k_quant_w<<<(D_DIM * D_DIM / 4) / 256, 256, 0, stream>>>(W, keys, wq);
  k_quant_fwht<<<rows, 256, 0, stream>>>(x, keys, xq);
  k_gemm<<<dim3(rows / 128, D_DIM / 128), 256, 0, stream>>>(xq, wq, keys, bias, out);
}

// Round 10
// 875.464 us; speedup vs baseline: 1.1270x; 1.1270x over previous
//
#include <hip/hip_runtime.h>
#include <hip/hip_bf16.h>
#include <stdint.h>

// HBitLinear: out = ((quant4(x@H))@H) @ (ternary(W))^T + bias
// D=4096, rows = B*S = 8192. H = Sylvester Hadamard / 64 (symmetric).

#define D_DIM 4096

typedef __attribute__((ext_vector_type(8))) short bf16x8;   // 8 bf16 = 4 VGPRs
typedef __attribute__((ext_vector_type(4))) float f32x4;

// ---- order-preserving float<->uint keys for atomic min/max ----
__device__ __forceinline__ unsigned f2ord(float f) {
  unsigned u = __float_as_uint(f);
  return (u & 0x80000000u) ? ~u : (u | 0x80000000u);
}
__device__ __forceinline__ float ord2f(unsigned k) {
  return (k & 0x80000000u) ? __uint_as_float(k & 0x7fffffffu) : __uint_as_float(~k);
}
// float -> bf16 bits, round-nearest-even (no NaN inputs here)
__device__ __forceinline__ unsigned f2bf(float f) {
  unsigned u = __float_as_uint(f);
  return ((u + 0x7fffu + ((u >> 16) & 1u)) >> 16) & 0xffffu;
}

// ws layout: [0..63] uint scalars: keys[0]=max|W|, keys[1]=min t, keys[2]=max t
//            +256B : xq  (rows*4096 bf16)  = 64 MiB
//            +256B+64MiB : wq (4096^2 bf16, ternary +-1/0, scale folded out) = 32 MiB

__global__ void k_init(unsigned* keys) {
  keys[0] = 0u;            // max|W| key (values >= 0 -> key >= 0x80000000)
  keys[1] = 0xFFFFFFFFu;   // min t key
  keys[2] = 0u;            // max t key
}

// ---- max |W| reduce ----
__global__ __launch_bounds__(256) void k_wabs(const float* __restrict__ W, unsigned* keys) {
  float m = 0.0f;
  const int n4 = (D_DIM * D_DIM) / 4;
  for (int i = blockIdx.x * 256 + threadIdx.x; i < n4; i += gridDim.x * 256) {
    float4 v = ((const float4*)W)[i];
    m = fmaxf(m, fmaxf(fmaxf(fabsf(v.x), fabsf(v.y)), fmaxf(fabsf(v.z), fabsf(v.w))));
  }
  #pragma unroll
  for (int off = 32; off; off >>= 1) m = fmaxf(m, __shfl_down(m, off));
  __shared__ float sm[4];
  if ((threadIdx.x & 63) == 0) sm[threadIdx.x >> 6] = m;
  __syncthreads();
  if (threadIdx.x == 0) {
    m = fmaxf(fmaxf(sm[0], sm[1]), fmaxf(sm[2], sm[3]));
    atomicMax(keys + 0, f2ord(m));
  }
}

// ---- ternary weight quant: wq = 0 if |W/s|<0.5 else sign, stored as bf16 ±1 ----
__global__ __launch_bounds__(256) void k_quant_w(const float* __restrict__ W,
                                                 const unsigned* __restrict__ keys,
                                                 unsigned short* __restrict__ wq) {
  const float scale = ord2f(keys[0]);   // >0 for this input
  const int i = blockIdx.x * 256 + threadIdx.x;   // over float4
  float4 v = ((const float4*)W)[i];
  ushort4 o;
  {
    float wn = v.x / scale;
    o.x = (fabsf(wn) < 0.5f) ? 0 : ((wn < 0.0f) ? 0xBF80u : 0x3F80u);
    wn = v.y / scale;
    o.y = (fabsf(wn) < 0.5f) ? 0 : ((wn < 0.0f) ? 0xBF80u : 0x3F80u);
    wn = v.z / scale;
    o.z = (fabsf(wn) < 0.5f) ? 0 : ((wn < 0.0f) ? 0xBF80u : 0x3F80u);
    wn = v.w / scale;
    o.w = (fabsf(wn) < 0.5f) ? 0 : ((wn < 0.0f) ? 0xBF80u : 0x3F80u);
  }
  ((ushort4*)wq)[i] = o;
}

// ============================================================================
// Wave-autonomous register FWHT on one 4096-float row per 64-lane wave.
// Element e (12 bits): j=e[1:0] (float4 lane-component), l=e[7:2] (lane),
// rv=e[11:8] (register vector). Lane l holds v[rv][j] = elem rv*256+l*4+j.
//   phase R1: butterflies on bits {8,9,10,11} (across rv) and {0,1} (in-vec)
//   transpose via XOR-swizzled LDS -> lane l' holds w[m] = elem with
//      rv=l'>>2, j=l'&3, m=e[7:2] varying 0..63
//   phase R2: butterflies on bits {2..7} (across m)
// LDS float addr(e) = rv*256 + ((m ^ (rv&7))<<2) + j   [bank-conflict-free:
//   b128 writes contiguous-permuted 1KB/instr; b32 reads spread 32 banks 2-way]
// ============================================================================

__device__ __forceinline__ void bfly_rv(f32x4 v[16]) {
  #pragma unroll
  for (int b = 1; b < 16; b <<= 1)
    #pragma unroll
    for (int rv = 0; rv < 16; ++rv)
      if (!(rv & b)) {
        f32x4 a = v[rv], c = v[rv | b];
        v[rv] = a + c;
        v[rv | b] = a - c;
      }
  // bits 0,1 within each float4
  #pragma unroll
  for (int rv = 0; rv < 16; ++rv) {
    f32x4 a = v[rv];
    f32x4 t = {a.x + a.y, a.x - a.y, a.z + a.w, a.z - a.w};
    v[rv] = (f32x4){t.x + t.z, t.y + t.w, t.x - t.z, t.y - t.w};
  }
}

__device__ __forceinline__ void bfly_m(float w[64]) {
  #pragma unroll
  for (int b = 1; b < 64; b <<= 1)
    #pragma unroll
    for (int m = 0; m < 64; ++m)
      if (!(m & b)) {
        float a = w[m], c = w[m | b];
        w[m] = a + c;
        w[m | b] = a - c;
      }
}

__device__ __forceinline__ void xpose_v2w(float* lds, const f32x4 v[16], float w[64], int l) {
  #pragma unroll
  for (int rv = 0; rv < 16; ++rv)
    *(f32x4*)&lds[rv * 256 + ((l ^ (rv & 7)) << 2)] = v[rv];
  __syncthreads();
  const int rvL = l >> 2, jL = l & 3;
  #pragma unroll
  for (int m = 0; m < 64; ++m)
    w[m] = lds[rvL * 256 + ((m ^ (rvL & 7)) << 2) + jL];
}

__device__ __forceinline__ void xpose_w2v(float* lds, const float w[64], f32x4 v[16], int l) {
  const int rvL = l >> 2, jL = l & 3;
  #pragma unroll
  for (int m = 0; m < 64; ++m)
    lds[rvL * 256 + ((m ^ (rvL & 7)) << 2) + jL] = w[m];
  __syncthreads();
  #pragma unroll
  for (int rv = 0; rv < 16; ++rv)
    v[rv] = *(const f32x4*)&lds[rv * 256 + ((l ^ (rv & 7)) << 2)];
}

// ---- pass 1: t = x@H per row, global min/max via atomics (t not stored) ----
__global__ __launch_bounds__(64) void k_fwht_minmax(const float* __restrict__ x,
                                                    unsigned* keys) {
  __shared__ float lds[D_DIM];
  const int l = threadIdx.x;
  const f32x4* src = (const f32x4*)(x + (size_t)blockIdx.x * D_DIM);
  f32x4 v[16];
  #pragma unroll
  for (int rv = 0; rv < 16; ++rv) v[rv] = src[rv * 64 + l];
  bfly_rv(v);
  float w[64];
  xpose_v2w(lds, v, w, l);
  bfly_m(w);
  float mn = 1e30f, mx = -1e30f;
  #pragma unroll
  for (int m = 0; m < 64; ++m) {
    const float t = w[m] * (1.0f / 64.0f);
    mn = fminf(mn, t);
    mx = fmaxf(mx, t);
  }
  #pragma unroll
  for (int off = 32; off; off >>= 1) {
    mn = fminf(mn, __shfl_down(mn, off));
    mx = fmaxf(mx, __shfl_down(mx, off));
  }
  if (l == 0) {
    atomicMin(keys + 1, f2ord(mn));
    atomicMax(keys + 2, f2ord(mx));
  }
}

// ---- pass 2: recompute t, 4-bit affine quant/dequant, second FWHT, pack bf16 ----
__global__ __launch_bounds__(64) void k_quant_fwht(const float* __restrict__ x,
                                                   const unsigned* __restrict__ keys,
                                                   unsigned short* __restrict__ xq) {
  __shared__ float lds[D_DIM];
  const int l = threadIdx.x;
  const f32x4* src = (const f32x4*)(x + (size_t)blockIdx.x * D_DIM);
  f32x4 v[16];
  #pragma unroll
  for (int rv = 0; rv < 16; ++rv) v[rv] = src[rv * 64 + l];
  bfly_rv(v);
  float w[64];
  xpose_v2w(lds, v, w, l);
  bfly_m(w);

  // 4-bit affine quant/dequant on t = w/64 (full FWHT done at this point)
  const float tmin = ord2f(keys[1]);
  const float tmax = ord2f(keys[2]);
  const float scale = (tmax - tmin) / 15.0f;       // (qmax-qmin)=15
  const float zp = -8.0f - rintf(tmin / scale);    // jnp.round = rintf (half-even)
  #pragma unroll
  for (int m = 0; m < 64; ++m) {
    const float t = w[m] * (1.0f / 64.0f);
    float q = rintf(t / scale + zp);
    q = fminf(fmaxf(q, -8.0f), 7.0f);
    w[m] = scale * (q - zp);
  }

  // second FWHT: bits 2..7 in current layout, transpose back, bits {8..11,0,1}
  bfly_m(w);
  __syncthreads();               // lds reuse: all reads of transpose-1 done
  xpose_w2v(lds, w, v, l);
  bfly_rv(v);

  // pack to bf16 with the 1/64 normalization, 8B/lane coalesced stores
  ushort4* dst = (ushort4*)(xq + (size_t)blockIdx.x * D_DIM);
  #pragma unroll
  for (int rv = 0; rv < 16; ++rv) {
    ushort4 o;
    o.x = (unsigned short)f2bf(v[rv].x * (1.0f / 64.0f));
    o.y = (unsigned short)f2bf(v[rv].y * (1.0f / 64.0f));
    o.z = (unsigned short)f2bf(v[rv].z * (1.0f / 64.0f));
    o.w = (unsigned short)f2bf(v[rv].w * (1.0f / 64.0f));
    dst[rv * 64 + l] = o;
  }
}

// ---- GEMM: out[m][n] = wscale * sum_k Xq[m][k]*Wsgn[n][k] + bias[n] ----
// 128x128 tile, BK=32, 4 waves (2x2), 4x4 frags of 16x16x32 bf16,
// global_load_lds width 16, linear LDS, double-buffered 2-phase K-loop
// (T3-minimum: issue STAGE(next) before ds_read+MFMA(cur), 1 barrier/iter).
typedef const __attribute__((address_space(1))) unsigned int gu32;
typedef __attribute__((address_space(3))) unsigned int lu32;
#define GLL(g, l) __builtin_amdgcn_global_load_lds((gu32*)(g), (lu32*)(l), 16, 0, 0)

__global__ __launch_bounds__(256) void k_gemm(const unsigned short* __restrict__ Xq,
                                              const unsigned short* __restrict__ Wq,
                                              const unsigned* __restrict__ keys,
                                              const float* __restrict__ bias,
                                              float* __restrict__ out) {
  __shared__ unsigned short lA[2][128 * 32];
  __shared__ unsigned short lB[2][128 * 32];
  const int tid = threadIdx.x;
  const int wave = tid >> 6, lane = tid & 63;
  const int wr = wave >> 1, wc = wave & 1;
  const size_t rowA0 = (size_t)blockIdx.x * 128;
  const size_t rowB0 = (size_t)blockIdx.y * 128;

  // staging: element e = wave*512 + lane*8 (+2048 for second half) of 128x32 tile
  const int e = wave * 512 + lane * 8;
  const int er = e >> 5, ec = e & 31;
  const unsigned short* gA0 = Xq + (rowA0 + er) * D_DIM + ec;
  const unsigned short* gA1 = Xq + (rowA0 + 64 + er) * D_DIM + ec;
  const unsigned short* gB0 = Wq + (rowB0 + er) * D_DIM + ec;
  const unsigned short* gB1 = Wq + (rowB0 + 64 + er) * D_DIM + ec;

  f32x4 acc[4][4] = {};

  // prologue: stage tile 0 into buffer 0
  {
    unsigned short* a = &lA[0][wave * 512];
    unsigned short* b = &lB[0][wave * 512];
    GLL(gA0, a);
    GLL(gA1, a + 2048);
    GLL(gB0, b);
    GLL(gB1, b + 2048);
  }
  __syncthreads();

  int cur = 0;
  for (int kt = 0; kt < D_DIM / 32; ++kt) {
    // issue next-tile loads into the other buffer BEFORE compute (overlap)
    if (kt + 1 < D_DIM / 32) {
      const int ko = (kt + 1) * 32;
      unsigned short* a = &lA[cur ^ 1][wave * 512];
      unsigned short* b = &lB[cur ^ 1][wave * 512];
      GLL(gA0 + ko, a);
      GLL(gA1 + ko, a + 2048);
      GLL(gB0 + ko, b);
      GLL(gB1 + ko, b + 2048);
    }
    bf16x8 af[4], bfr[4];
    #pragma unroll
    for (int i = 0; i < 4; ++i)
      af[i] = *(const bf16x8*)&lA[cur][(wr * 64 + i * 16 + (lane & 15)) * 32 + (lane >> 4) * 8];
    #pragma unroll
    for (int i = 0; i < 4; ++i)
      bfr[i] = *(const bf16x8*)&lB[cur][(wc * 64 + i * 16 + (lane & 15)) * 32 + (lane >> 4) * 8];
    #pragma unroll
    for (int mi = 0; mi < 4; ++mi)
      #pragma unroll
      for (int ni = 0; ni < 4; ++ni)
        acc[mi][ni] = __builtin_amdgcn_mfma_f32_16x16x32_bf16(af[mi], bfr[ni], acc[mi][ni], 0, 0, 0);
    __syncthreads();   // drains vmcnt(0): next buffer staged; all reads of cur done
    cur ^= 1;
  }

  const float wscale = ord2f(keys[0]);
  #pragma unroll
  for (int mi = 0; mi < 4; ++mi)
    #pragma unroll
    for (int ni = 0; ni < 4; ++ni)
      #pragma unroll
      for (int r = 0; r < 4; ++r) {
        const size_t row = rowA0 + wr * 64 + mi * 16 + (lane >> 4) * 4 + r;
        const size_t col = rowB0 + wc * 64 + ni * 16 + (lane & 15);
        out[row * D_DIM + col] = acc[mi][ni][r] * wscale + bias[col];
      }
}

extern "C" void kernel_launch(void* const* d_in, const int* in_sizes, int n_in,
                              void* d_out, int out_size, void* d_ws, size_t ws_size,
                              hipStream_t stream) {
  const float* x    = (const float*)d_in[0];
  const float* W    = (const float*)d_in[1];
  const float* bias = (const float*)d_in[2];
  float* out = (float*)d_out;

  const int rows = in_sizes[0] / D_DIM;   // 8192

  unsigned* keys = (unsigned*)d_ws;
  unsigned short* xq = (unsigned short*)((char*)d_ws + 256);
  unsigned short* wq = (unsigned short*)((char*)d_ws + 256 + (size_t)rows * D_DIM * 2);

  k_init<<<1, 1, 0, stream>>>(keys);
  k_wabs<<<1024, 256, 0, stream>>>(W, keys);
  k_fwht_minmax<<<rows, 64, 0, stream>>>(x, keys);
  k_quant_w<<<(D_DIM * D_DIM / 4) / 256, 256, 0, stream>>>(W, keys, wq);
  k_quant_fwht<<<rows, 64, 0, stream>>>(x, keys, xq);
  k_gemm<<<dim3(rows / 128, D_DIM / 128), 256, 0, stream>>>(xq, wq, keys, bias, out);
}